// Round 1
// baseline (260.120 us; speedup 1.0000x reference)
//
#include <hip/hip_runtime.h>
#include <hip/hip_bf16.h>

#define K_DIM 512
#define N_DIM 512

typedef __attribute__((ext_vector_type(8))) short s8v;   // 8 bf16 bit-patterns (4 VGPR)
typedef __attribute__((ext_vector_type(4))) short s4v;
typedef __attribute__((ext_vector_type(4))) float f4v;

__device__ __forceinline__ short f2bf(float f) {
  union { float f; unsigned u; } v; v.f = f;
  unsigned r = (v.u + 0x7FFFu + ((v.u >> 16) & 1u)) >> 16;  // RNE
  return (short)r;
}
__device__ __forceinline__ float bflo(unsigned u) {
  union { unsigned u; float f; } v; v.u = u << 16; return v.f;
}
__device__ __forceinline__ float bfhi(unsigned u) {
  union { unsigned u; float f; } v; v.u = u & 0xffff0000u; return v.f;
}

// Detect whether edge_index arrived as int64 (odd int32 words all zero) or int32.
__global__ void k_flag(const int* __restrict__ e32, int* __restrict__ flag) {
  int t = threadIdx.x;
  int v = e32[2 * t + 1];
  unsigned long long m = __ballot(v == 0);
  if (t == 0) flag[0] = (m == ~0ULL) ? 1 : 0;
}

__global__ void k_convW(const float* __restrict__ W, short* __restrict__ Wb) {
  int i = (blockIdx.x * blockDim.x + threadIdx.x) * 4;
  float4 f = *(const float4*)(W + i);
  s4v s; s[0] = f2bf(f.x); s[1] = f2bf(f.y); s[2] = f2bf(f.z); s[3] = f2bf(f.w);
  *(s4v*)(Wb + i) = s;
}

__global__ void k_hist(const int* __restrict__ e32, const int* __restrict__ flag,
                       int* __restrict__ outdeg, int* __restrict__ indeg, int E) {
  int i = blockIdx.x * blockDim.x + threadIdx.x;
  if (i >= E) return;
  int st = flag[0] ? 2 : 1;
  int r = e32[(size_t)i * st];
  int c = e32[(size_t)(E + i) * st];
  atomicAdd(&outdeg[r], 1);
  atomicAdd(&indeg[c], 1);
}

__global__ void k_dis(const int* __restrict__ outdeg, float* __restrict__ dis, int n) {
  int i = blockIdx.x * blockDim.x + threadIdx.x;
  if (i < n) dis[i] = rsqrtf((float)(outdeg[i] + 1));  // +1 self-loop
}

__global__ void k_scan_a(const int* __restrict__ in, int* __restrict__ part, int n) {
  __shared__ int sm[256];
  int i = blockIdx.x * 256 + threadIdx.x;
  sm[threadIdx.x] = (i < n) ? in[i] : 0;
  __syncthreads();
  for (int off = 128; off > 0; off >>= 1) {
    if (threadIdx.x < off) sm[threadIdx.x] += sm[threadIdx.x + off];
    __syncthreads();
  }
  if (threadIdx.x == 0) part[blockIdx.x] = sm[0];
}

__global__ void k_scan_b(int* __restrict__ part, int nb, int* __restrict__ row_start, int n) {
  __shared__ int sm[256];
  int t = threadIdx.x;
  int v = (t < nb) ? part[t] : 0;
  sm[t] = v; __syncthreads();
  for (int off = 1; off < 256; off <<= 1) {
    int a = (t >= off) ? sm[t - off] : 0;
    __syncthreads();
    sm[t] += a;
    __syncthreads();
  }
  part[t] = sm[t] - v;                  // exclusive block offsets
  if (t == 255) row_start[n] = sm[255]; // grand total (= E)
}

__global__ void k_scan_c(const int* __restrict__ in, const int* __restrict__ part,
                         int* __restrict__ row_start, int* __restrict__ cursor, int n) {
  __shared__ int sm[256];
  int i = blockIdx.x * 256 + threadIdx.x;
  int v = (i < n) ? in[i] : 0;
  sm[threadIdx.x] = v; __syncthreads();
  for (int off = 1; off < 256; off <<= 1) {
    int a = (threadIdx.x >= off) ? sm[threadIdx.x - off] : 0;
    __syncthreads();
    sm[threadIdx.x] += a;
    __syncthreads();
  }
  if (i < n) {
    int excl = part[blockIdx.x] + sm[threadIdx.x] - v;
    row_start[i] = excl;
    cursor[i] = excl;
  }
}

__global__ void k_fill(const int* __restrict__ e32, const int* __restrict__ flag,
                       int* __restrict__ cursor, int* __restrict__ csr, int E) {
  int i = blockIdx.x * blockDim.x + threadIdx.x;
  if (i >= E) return;
  int st = flag[0] ? 2 : 1;
  int r = e32[(size_t)i * st];
  int c = e32[(size_t)(E + i) * st];
  int p = atomicAdd(&cursor[c], 1);
  csr[p] = r;
}

// h[M][512] (bf16) = x[M][512] (f32) @ Wb[512][512]^T (bf16) + bias
// 128x128 tile, 4 waves (2x2), wave tile 64x64 = 4x4 frags of 16x16x32 MFMA.
__global__ __launch_bounds__(256) void k_gemm(const float* __restrict__ x,
    const short* __restrict__ Wb, const float* __restrict__ bias,
    short* __restrict__ h, int M) {
  __shared__ __align__(16) short As[128][40];  // +8 pad: stride 80B = 20 banks -> 2-way max
  __shared__ __align__(16) short Bs[128][40];
  int m0 = blockIdx.x * 128, n0 = blockIdx.y * 128;
  int tid = threadIdx.x;
  int lane = tid & 63;
  int wv = tid >> 6, wr = wv >> 1, wc = wv & 1;
  int la = lane & 15, lg = lane >> 4;
  int sr = tid >> 1, sc = (tid & 1) * 16;
  const float* xrow = x + (size_t)(m0 + sr) * K_DIM;
  const short* wrow = Wb + (size_t)(n0 + sr) * K_DIM;
  bool aok = (m0 + sr) < M;
  f4v acc[4][4] = {};
  for (int kk = 0; kk < K_DIM; kk += 32) {
    __syncthreads();
    s8v a0, a1;
    #pragma unroll
    for (int q = 0; q < 8; ++q) { a0[q] = 0; a1[q] = 0; }
    if (aok) {
      float4 f0 = *(const float4*)(xrow + kk + sc);
      float4 f1 = *(const float4*)(xrow + kk + sc + 4);
      float4 f2 = *(const float4*)(xrow + kk + sc + 8);
      float4 f3 = *(const float4*)(xrow + kk + sc + 12);
      a0[0] = f2bf(f0.x); a0[1] = f2bf(f0.y); a0[2] = f2bf(f0.z); a0[3] = f2bf(f0.w);
      a0[4] = f2bf(f1.x); a0[5] = f2bf(f1.y); a0[6] = f2bf(f1.z); a0[7] = f2bf(f1.w);
      a1[0] = f2bf(f2.x); a1[1] = f2bf(f2.y); a1[2] = f2bf(f2.z); a1[3] = f2bf(f2.w);
      a1[4] = f2bf(f3.x); a1[5] = f2bf(f3.y); a1[6] = f2bf(f3.z); a1[7] = f2bf(f3.w);
    }
    *(s8v*)(&As[sr][sc]) = a0;
    *(s8v*)(&As[sr][sc + 8]) = a1;
    uint4 b0 = *(const uint4*)(wrow + kk + sc);
    uint4 b1 = *(const uint4*)(wrow + kk + sc + 8);
    *(uint4*)(&Bs[sr][sc]) = b0;
    *(uint4*)(&Bs[sr][sc + 8]) = b1;
    __syncthreads();
    s8v af[4], bfr[4];
    #pragma unroll
    for (int i = 0; i < 4; ++i)
      af[i] = *(const s8v*)(&As[64 * wr + 16 * i + la][8 * lg]);
    #pragma unroll
    for (int j = 0; j < 4; ++j)
      bfr[j] = *(const s8v*)(&Bs[64 * wc + 16 * j + la][8 * lg]);
    #pragma unroll
    for (int i = 0; i < 4; ++i)
      #pragma unroll
      for (int j = 0; j < 4; ++j)
        acc[i][j] = __builtin_amdgcn_mfma_f32_16x16x32_bf16(af[i], bfr[j], acc[i][j], 0, 0, 0);
  }
  #pragma unroll
  for (int i = 0; i < 4; ++i) {
    #pragma unroll
    for (int j = 0; j < 4; ++j) {
      int col = n0 + 64 * wc + 16 * j + la;
      float bv = bias[col];
      #pragma unroll
      for (int r = 0; r < 4; ++r) {
        int row = m0 + 64 * wr + 16 * i + lg * 4 + r;
        if (row < M) h[(size_t)row * N_DIM + col] = f2bf(acc[i][j][r] + bv);
      }
    }
  }
}

// One wave per dst node: register-accumulate norm-weighted gather of h rows, ReLU, store.
__global__ __launch_bounds__(256) void k_scatter(const short* __restrict__ h,
    const float* __restrict__ dis, const int* __restrict__ row_start,
    const int* __restrict__ csr, float* __restrict__ out, int n) {
  int v = blockIdx.x * 4 + (threadIdx.x >> 6);
  if (v >= n) return;
  int lane = threadIdx.x & 63;
  const short* hl = h + lane * 8;
  float dv = dis[v];
  float acc[8];
  {
    uint4 r = *(const uint4*)(hl + (size_t)v * N_DIM);  // self-loop: dis[v]^2 * h[v]
    float w = dv * dv;
    acc[0] = w * bflo(r.x); acc[1] = w * bfhi(r.x);
    acc[2] = w * bflo(r.y); acc[3] = w * bfhi(r.y);
    acc[4] = w * bflo(r.z); acc[5] = w * bfhi(r.z);
    acc[6] = w * bflo(r.w); acc[7] = w * bfhi(r.w);
  }
  int s = row_start[v], e = row_start[v + 1];
  for (int idx = s; idx < e; ++idx) {
    int src = csr[idx];
    float nrm = dis[src] * dv;
    uint4 r = *(const uint4*)(hl + (size_t)src * N_DIM);
    acc[0] += nrm * bflo(r.x); acc[1] += nrm * bfhi(r.x);
    acc[2] += nrm * bflo(r.y); acc[3] += nrm * bfhi(r.y);
    acc[4] += nrm * bflo(r.z); acc[5] += nrm * bfhi(r.z);
    acc[6] += nrm * bflo(r.w); acc[7] += nrm * bfhi(r.w);
  }
  float* op = out + (size_t)v * N_DIM + lane * 8;
  float4 o0, o1;
  o0.x = fmaxf(acc[0], 0.f); o0.y = fmaxf(acc[1], 0.f);
  o0.z = fmaxf(acc[2], 0.f); o0.w = fmaxf(acc[3], 0.f);
  o1.x = fmaxf(acc[4], 0.f); o1.y = fmaxf(acc[5], 0.f);
  o1.z = fmaxf(acc[6], 0.f); o1.w = fmaxf(acc[7], 0.f);
  *(float4*)op = o0;
  *(float4*)(op + 4) = o1;
}

extern "C" void kernel_launch(void* const* d_in, const int* in_sizes, int n_in,
                              void* d_out, int out_size, void* d_ws, size_t ws_size,
                              hipStream_t stream) {
  const float* x = (const float*)d_in[0];
  const int* e32 = (const int*)d_in[1];
  const float* W = (const float*)d_in[2];
  const float* bias = (const float*)d_in[3];
  float* out = (float*)d_out;
  int M = in_sizes[0] / K_DIM;   // 50000
  int E = in_sizes[1] / 2;       // 400000

  char* ws = (char*)d_ws;
  size_t off = 0;
  auto alloc = [&](size_t bytes) {
    void* p = ws + off;
    off = (off + bytes + 255) & ~(size_t)255;
    return p;
  };
  short* Wb      = (short*)alloc((size_t)N_DIM * K_DIM * 2);
  short* h       = (short*)alloc((size_t)M * N_DIM * 2);
  float* dis     = (float*)alloc((size_t)M * 4);
  int*   outdeg  = (int*)alloc((size_t)M * 4);
  int*   indeg   = (int*)alloc((size_t)M * 4);
  int*   rstart  = (int*)alloc((size_t)(M + 1) * 4);
  int*   cursor  = (int*)alloc((size_t)M * 4);
  int*   part    = (int*)alloc(256 * 4);
  int*   csr     = (int*)alloc((size_t)E * 4);
  int*   flag    = (int*)alloc(4);
  if (off > ws_size) return;  // workspace too small: fail loudly via absmax

  hipMemsetAsync(outdeg, 0, (size_t)M * 4, stream);
  hipMemsetAsync(indeg, 0, (size_t)M * 4, stream);
  k_flag<<<1, 64, 0, stream>>>(e32, flag);
  k_convW<<<(N_DIM * K_DIM / 4 + 255) / 256, 256, 0, stream>>>(W, Wb);
  k_hist<<<(E + 255) / 256, 256, 0, stream>>>(e32, flag, outdeg, indeg, E);
  k_dis<<<(M + 255) / 256, 256, 0, stream>>>(outdeg, dis, M);
  int nscan = (M + 255) / 256;  // 196 (must be <= 256)
  k_scan_a<<<nscan, 256, 0, stream>>>(indeg, part, M);
  k_scan_b<<<1, 256, 0, stream>>>(part, nscan, rstart, M);
  k_scan_c<<<nscan, 256, 0, stream>>>(indeg, part, rstart, cursor, M);
  k_fill<<<(E + 255) / 256, 256, 0, stream>>>(e32, flag, cursor, csr, E);
  k_gemm<<<dim3((M + 127) / 128, N_DIM / 128), 256, 0, stream>>>(x, Wb, bias, h, M);
  k_scatter<<<(M + 3) / 4, 256, 0, stream>>>(h, dis, rstart, csr, out, M);
}

// Round 3
// 242.913 us; speedup vs baseline: 1.0708x; 1.0708x over previous
//
#include <hip/hip_runtime.h>
#include <hip/hip_bf16.h>

#define K_DIM 512
#define N_DIM 512

typedef __attribute__((ext_vector_type(8))) short s8v;   // 8 bf16 bit-patterns (4 VGPR)
typedef __attribute__((ext_vector_type(4))) short s4v;
typedef __attribute__((ext_vector_type(4))) float f4v;

__device__ __forceinline__ short f2bf(float f) {
  union { float f; unsigned u; } v; v.f = f;
  unsigned r = (v.u + 0x7FFFu + ((v.u >> 16) & 1u)) >> 16;  // RNE
  return (short)r;
}
__device__ __forceinline__ float bflo(unsigned u) {
  union { unsigned u; float f; } v; v.u = u << 16; return v.f;
}
__device__ __forceinline__ float bfhi(unsigned u) {
  union { unsigned u; float f; } v; v.u = u & 0xffff0000u; return v.f;
}

// async global->LDS, 16B per lane. LDS dest must be the wave-uniform base
// (HW scatters lane*16); global src is per-lane.
__device__ __forceinline__ void gload16(const void* g, void* l) {
  __builtin_amdgcn_global_load_lds(
      (const __attribute__((address_space(1))) void*)g,
      (__attribute__((address_space(3))) void*)l, 16, 0, 0);
}

// Detect whether edge_index arrived as int64 (odd int32 words all zero) or int32.
__global__ void k_flag(const int* __restrict__ e32, int* __restrict__ flag) {
  int t = threadIdx.x;
  int v = e32[2 * t + 1];
  unsigned long long m = __ballot(v == 0);
  if (t == 0) flag[0] = (m == ~0ULL) ? 1 : 0;
}

__global__ void k_convW(const float* __restrict__ W, short* __restrict__ Wb) {
  int i = (blockIdx.x * blockDim.x + threadIdx.x) * 4;
  float4 f = *(const float4*)(W + i);
  s4v s; s[0] = f2bf(f.x); s[1] = f2bf(f.y); s[2] = f2bf(f.z); s[3] = f2bf(f.w);
  *(s4v*)(Wb + i) = s;
}

__global__ void k_hist(const int* __restrict__ e32, const int* __restrict__ flag,
                       int* __restrict__ outdeg, int* __restrict__ indeg, int E) {
  int i = blockIdx.x * blockDim.x + threadIdx.x;
  if (i >= E) return;
  int st = flag[0] ? 2 : 1;
  int r = e32[(size_t)i * st];
  int c = e32[(size_t)(E + i) * st];
  atomicAdd(&outdeg[r], 1);
  atomicAdd(&indeg[c], 1);
}

__global__ void k_dis(const int* __restrict__ outdeg, float* __restrict__ dis, int n) {
  int i = blockIdx.x * blockDim.x + threadIdx.x;
  if (i < n) dis[i] = rsqrtf((float)(outdeg[i] + 1));  // +1 self-loop
}

__global__ void k_scan_a(const int* __restrict__ in, int* __restrict__ part, int n) {
  __shared__ int sm[256];
  int i = blockIdx.x * 256 + threadIdx.x;
  sm[threadIdx.x] = (i < n) ? in[i] : 0;
  __syncthreads();
  for (int off = 128; off > 0; off >>= 1) {
    if (threadIdx.x < off) sm[threadIdx.x] += sm[threadIdx.x + off];
    __syncthreads();
  }
  if (threadIdx.x == 0) part[blockIdx.x] = sm[0];
}

__global__ void k_scan_b(int* __restrict__ part, int nb, int* __restrict__ row_start, int n) {
  __shared__ int sm[256];
  int t = threadIdx.x;
  int v = (t < nb) ? part[t] : 0;
  sm[t] = v; __syncthreads();
  for (int off = 1; off < 256; off <<= 1) {
    int a = (t >= off) ? sm[t - off] : 0;
    __syncthreads();
    sm[t] += a;
    __syncthreads();
  }
  part[t] = sm[t] - v;                  // exclusive block offsets
  if (t == 255) row_start[n] = sm[255]; // grand total (= E)
}

__global__ void k_scan_c(const int* __restrict__ in, const int* __restrict__ part,
                         int* __restrict__ row_start, int* __restrict__ cursor, int n) {
  __shared__ int sm[256];
  int i = blockIdx.x * 256 + threadIdx.x;
  int v = (i < n) ? in[i] : 0;
  sm[threadIdx.x] = v; __syncthreads();
  for (int off = 1; off < 256; off <<= 1) {
    int a = (threadIdx.x >= off) ? sm[threadIdx.x - off] : 0;
    __syncthreads();
    sm[threadIdx.x] += a;
    __syncthreads();
  }
  if (i < n) {
    int excl = part[blockIdx.x] + sm[threadIdx.x] - v;
    row_start[i] = excl;
    cursor[i] = excl;
  }
}

__global__ void k_fill(const int* __restrict__ e32, const int* __restrict__ flag,
                       int* __restrict__ cursor, int* __restrict__ csr, int E) {
  int i = blockIdx.x * blockDim.x + threadIdx.x;
  if (i >= E) return;
  int st = flag[0] ? 2 : 1;
  int r = e32[(size_t)i * st];
  int c = e32[(size_t)(E + i) * st];
  int p = atomicAdd(&cursor[c], 1);
  csr[p] = r;
}

// h[M][512] (bf16) = x[M][512] (f32) @ Wb[512][512]^T (bf16) + bias
// 128x128 tile, BK=32, 4 waves (2x2), wave tile 64x64 = 4x4 frags of 16x16x32.
// Double-buffered LDS, 2-phase schedule (T3 minimum): issue next-tile loads,
// compute current, one __syncthreads per K-step. B staged via global_load_lds
// (linear LDS); A reg-staged f32->bf16 into padded LDS.
__global__ __launch_bounds__(256) void k_gemm(const float* __restrict__ x,
    const short* __restrict__ Wb, const float* __restrict__ bias,
    short* __restrict__ h, int M) {
  __shared__ __align__(16) short As[2][128][40];  // +8 pad: 80B stride -> 2-way max
  __shared__ __align__(16) short Bs[2][128][32];  // linear (global_load_lds dest)
  const int n0 = blockIdx.x * 128;   // N fastest: 4 N-tiles of same rows adjacent
  const int m0 = blockIdx.y * 128;
  const int tid = threadIdx.x;
  const int lane = tid & 63;
  const int wv = tid >> 6, wr = wv >> 1, wc = wv & 1;
  const int la = lane & 15, lg = lane >> 4;
  const int sr = tid >> 1, sc = (tid & 1) * 16;
  const float* xrow = x + (size_t)(m0 + sr) * K_DIM + sc;
  const bool aok = (m0 + sr) < M;
  // B staging: call q covers LDS rows q*64 + tid>>2, 16B chunk tid&3
  const short* bsrc = Wb + (size_t)(n0 + (tid >> 2)) * K_DIM + (tid & 3) * 8;
  char* bdst0 = (char*)&Bs[0][0][0] + wv * 1024;
  char* bdst1 = (char*)&Bs[1][0][0] + wv * 1024;

  f4v acc[4][4] = {};

  // prologue: stage k-tile 0 into buffer 0
  gload16(bsrc, bdst0);
  gload16(bsrc + (size_t)64 * K_DIM, bdst0 + 4096);
  {
    float4 f0{}, f1{}, f2{}, f3{};
    if (aok) {
      f0 = *(const float4*)(xrow);
      f1 = *(const float4*)(xrow + 4);
      f2 = *(const float4*)(xrow + 8);
      f3 = *(const float4*)(xrow + 12);
    }
    s8v v0, v1;
    v0[0] = f2bf(f0.x); v0[1] = f2bf(f0.y); v0[2] = f2bf(f0.z); v0[3] = f2bf(f0.w);
    v0[4] = f2bf(f1.x); v0[5] = f2bf(f1.y); v0[6] = f2bf(f1.z); v0[7] = f2bf(f1.w);
    v1[0] = f2bf(f2.x); v1[1] = f2bf(f2.y); v1[2] = f2bf(f2.z); v1[3] = f2bf(f2.w);
    v1[4] = f2bf(f3.x); v1[5] = f2bf(f3.y); v1[6] = f2bf(f3.z); v1[7] = f2bf(f3.w);
    *(s8v*)&As[0][sr][sc] = v0;
    *(s8v*)&As[0][sr][sc + 8] = v1;
  }
  __syncthreads();

  for (int kt = 0; kt < 16; ++kt) {
    const int cur = kt & 1;
    const int nxt = cur ^ 1;
    float4 f0{}, f1{}, f2{}, f3{};
    if (kt < 15) {
      const int kk = (kt + 1) * 32;
      char* bd = cur ? bdst0 : bdst1;
      gload16(bsrc + kk, bd);
      gload16(bsrc + kk + (size_t)64 * K_DIM, bd + 4096);
      if (aok) {
        f0 = *(const float4*)(xrow + kk);
        f1 = *(const float4*)(xrow + kk + 4);
        f2 = *(const float4*)(xrow + kk + 8);
        f3 = *(const float4*)(xrow + kk + 12);
      }
    }
    s8v a0 = *(const s8v*)&As[cur][64 * wr + la][8 * lg];
    s8v a1 = *(const s8v*)&As[cur][64 * wr + 16 + la][8 * lg];
    s8v a2 = *(const s8v*)&As[cur][64 * wr + 32 + la][8 * lg];
    s8v a3 = *(const s8v*)&As[cur][64 * wr + 48 + la][8 * lg];
    s8v b0 = *(const s8v*)&Bs[cur][64 * wc + la][8 * lg];
    s8v b1 = *(const s8v*)&Bs[cur][64 * wc + 16 + la][8 * lg];
    s8v b2 = *(const s8v*)&Bs[cur][64 * wc + 32 + la][8 * lg];
    s8v b3 = *(const s8v*)&Bs[cur][64 * wc + 48 + la][8 * lg];
    acc[0][0] = __builtin_amdgcn_mfma_f32_16x16x32_bf16(a0, b0, acc[0][0], 0, 0, 0);
    acc[0][1] = __builtin_amdgcn_mfma_f32_16x16x32_bf16(a0, b1, acc[0][1], 0, 0, 0);
    acc[0][2] = __builtin_amdgcn_mfma_f32_16x16x32_bf16(a0, b2, acc[0][2], 0, 0, 0);
    acc[0][3] = __builtin_amdgcn_mfma_f32_16x16x32_bf16(a0, b3, acc[0][3], 0, 0, 0);
    acc[1][0] = __builtin_amdgcn_mfma_f32_16x16x32_bf16(a1, b0, acc[1][0], 0, 0, 0);
    acc[1][1] = __builtin_amdgcn_mfma_f32_16x16x32_bf16(a1, b1, acc[1][1], 0, 0, 0);
    acc[1][2] = __builtin_amdgcn_mfma_f32_16x16x32_bf16(a1, b2, acc[1][2], 0, 0, 0);
    acc[1][3] = __builtin_amdgcn_mfma_f32_16x16x32_bf16(a1, b3, acc[1][3], 0, 0, 0);
    acc[2][0] = __builtin_amdgcn_mfma_f32_16x16x32_bf16(a2, b0, acc[2][0], 0, 0, 0);
    acc[2][1] = __builtin_amdgcn_mfma_f32_16x16x32_bf16(a2, b1, acc[2][1], 0, 0, 0);
    acc[2][2] = __builtin_amdgcn_mfma_f32_16x16x32_bf16(a2, b2, acc[2][2], 0, 0, 0);
    acc[2][3] = __builtin_amdgcn_mfma_f32_16x16x32_bf16(a2, b3, acc[2][3], 0, 0, 0);
    acc[3][0] = __builtin_amdgcn_mfma_f32_16x16x32_bf16(a3, b0, acc[3][0], 0, 0, 0);
    acc[3][1] = __builtin_amdgcn_mfma_f32_16x16x32_bf16(a3, b1, acc[3][1], 0, 0, 0);
    acc[3][2] = __builtin_amdgcn_mfma_f32_16x16x32_bf16(a3, b2, acc[3][2], 0, 0, 0);
    acc[3][3] = __builtin_amdgcn_mfma_f32_16x16x32_bf16(a3, b3, acc[3][3], 0, 0, 0);
    if (kt < 15) {
      s8v v0, v1;
      v0[0] = f2bf(f0.x); v0[1] = f2bf(f0.y); v0[2] = f2bf(f0.z); v0[3] = f2bf(f0.w);
      v0[4] = f2bf(f1.x); v0[5] = f2bf(f1.y); v0[6] = f2bf(f1.z); v0[7] = f2bf(f1.w);
      v1[0] = f2bf(f2.x); v1[1] = f2bf(f2.y); v1[2] = f2bf(f2.z); v1[3] = f2bf(f2.w);
      v1[4] = f2bf(f3.x); v1[5] = f2bf(f3.y); v1[6] = f2bf(f3.z); v1[7] = f2bf(f3.w);
      *(s8v*)&As[nxt][sr][sc] = v0;
      *(s8v*)&As[nxt][sr][sc + 8] = v1;
    }
    __syncthreads();  // drains vmcnt(0) lgkmcnt(0): staged tile visible, reads done
  }

  #pragma unroll
  for (int i = 0; i < 4; ++i) {
    #pragma unroll
    for (int j = 0; j < 4; ++j) {
      int col = n0 + 64 * wc + 16 * j + la;
      float bv = bias[col];
      #pragma unroll
      for (int r = 0; r < 4; ++r) {
        int row = m0 + 64 * wr + 16 * i + lg * 4 + r;
        if (row < M) h[(size_t)row * N_DIM + col] = f2bf(acc[i][j][r] + bv);
      }
    }
  }
}

__device__ __forceinline__ void acc8(float* acc, uint4 rv, float wv) {
  acc[0] += wv * bflo(rv.x); acc[1] += wv * bfhi(rv.x);
  acc[2] += wv * bflo(rv.y); acc[3] += wv * bfhi(rv.y);
  acc[4] += wv * bflo(rv.z); acc[5] += wv * bfhi(rv.z);
  acc[6] += wv * bflo(rv.w); acc[7] += wv * bfhi(rv.w);
}

// One wave per dst node; 2-way unrolled gather for ILP; scalar loop bounds.
__global__ __launch_bounds__(256) void k_scatter(const short* __restrict__ h,
    const float* __restrict__ dis, const int* __restrict__ row_start,
    const int* __restrict__ csr, float* __restrict__ out, int n) {
  int v = blockIdx.x * 4 + (threadIdx.x >> 6);
  if (v >= n) return;
  int lane = threadIdx.x & 63;
  const short* hl = h + lane * 8;
  float dv = dis[v];
  float acc[8];
  {
    uint4 r = *(const uint4*)(hl + (size_t)v * N_DIM);  // self-loop: dis[v]^2 * h[v]
    float w = dv * dv;
    acc[0] = w * bflo(r.x); acc[1] = w * bfhi(r.x);
    acc[2] = w * bflo(r.y); acc[3] = w * bfhi(r.y);
    acc[4] = w * bflo(r.z); acc[5] = w * bfhi(r.z);
    acc[6] = w * bflo(r.w); acc[7] = w * bfhi(r.w);
  }
  int s = __builtin_amdgcn_readfirstlane(row_start[v]);
  int e = __builtin_amdgcn_readfirstlane(row_start[v + 1]);
  int idx = s;
  for (; idx + 2 <= e; idx += 2) {
    int s0 = csr[idx];
    int s1 = csr[idx + 1];
    float w0 = dis[s0] * dv;
    float w1 = dis[s1] * dv;
    uint4 r0 = *(const uint4*)(hl + (size_t)s0 * N_DIM);
    uint4 r1 = *(const uint4*)(hl + (size_t)s1 * N_DIM);
    acc8(acc, r0, w0);
    acc8(acc, r1, w1);
  }
  if (idx < e) {
    int s0 = csr[idx];
    float w0 = dis[s0] * dv;
    uint4 r0 = *(const uint4*)(hl + (size_t)s0 * N_DIM);
    acc8(acc, r0, w0);
  }
  float* op = out + (size_t)v * N_DIM + lane * 8;
  float4 o0, o1;
  o0.x = fmaxf(acc[0], 0.f); o0.y = fmaxf(acc[1], 0.f);
  o0.z = fmaxf(acc[2], 0.f); o0.w = fmaxf(acc[3], 0.f);
  o1.x = fmaxf(acc[4], 0.f); o1.y = fmaxf(acc[5], 0.f);
  o1.z = fmaxf(acc[6], 0.f); o1.w = fmaxf(acc[7], 0.f);
  *(float4*)op = o0;
  *(float4*)(op + 4) = o1;
}

extern "C" void kernel_launch(void* const* d_in, const int* in_sizes, int n_in,
                              void* d_out, int out_size, void* d_ws, size_t ws_size,
                              hipStream_t stream) {
  const float* x = (const float*)d_in[0];
  const int* e32 = (const int*)d_in[1];
  const float* W = (const float*)d_in[2];
  const float* bias = (const float*)d_in[3];
  float* out = (float*)d_out;
  int M = in_sizes[0] / K_DIM;   // 50000
  int E = in_sizes[1] / 2;       // 400000

  char* ws = (char*)d_ws;
  size_t off = 0;
  auto alloc = [&](size_t bytes) {
    void* p = ws + off;
    off = (off + bytes + 255) & ~(size_t)255;
    return p;
  };
  short* Wb      = (short*)alloc((size_t)N_DIM * K_DIM * 2);
  short* h       = (short*)alloc((size_t)M * N_DIM * 2);
  float* dis     = (float*)alloc((size_t)M * 4);
  int*   outdeg  = (int*)alloc((size_t)M * 4);
  int*   indeg   = (int*)alloc((size_t)M * 4);
  int*   rstart  = (int*)alloc((size_t)(M + 1) * 4);
  int*   cursor  = (int*)alloc((size_t)M * 4);
  int*   part    = (int*)alloc(256 * 4);
  int*   csr     = (int*)alloc((size_t)E * 4);
  int*   flag    = (int*)alloc(4);
  if (off > ws_size) return;  // workspace too small: fail loudly via absmax

  (void)hipMemsetAsync(outdeg, 0, (size_t)M * 4, stream);
  (void)hipMemsetAsync(indeg, 0, (size_t)M * 4, stream);
  k_flag<<<1, 64, 0, stream>>>(e32, flag);
  k_convW<<<(N_DIM * K_DIM / 4 + 255) / 256, 256, 0, stream>>>(W, Wb);
  k_hist<<<(E + 255) / 256, 256, 0, stream>>>(e32, flag, outdeg, indeg, E);
  k_dis<<<(M + 255) / 256, 256, 0, stream>>>(outdeg, dis, M);
  int nscan = (M + 255) / 256;  // 196 (must be <= 256)
  k_scan_a<<<nscan, 256, 0, stream>>>(indeg, part, M);
  k_scan_b<<<1, 256, 0, stream>>>(part, nscan, rstart, M);
  k_scan_c<<<nscan, 256, 0, stream>>>(indeg, part, rstart, cursor, M);
  k_fill<<<(E + 255) / 256, 256, 0, stream>>>(e32, flag, cursor, csr, E);
  k_gemm<<<dim3(N_DIM / 128, (M + 127) / 128), 256, 0, stream>>>(x, Wb, bias, h, M);
  k_scatter<<<(M + 3) / 4, 256, 0, stream>>>(h, dis, rstart, csr, out, M);
}